// Round 14
// baseline (113.984 us; speedup 1.0000x reference)
//
#include <hip/hip_runtime.h>
#include <hip/hip_bf16.h>
#include <math.h>

constexpr int B = 4;
constexpr int N = 1024;
constexpr float NEGINF = -9000000000000000.0f;

// ---------- prep: 512 blocks (b x 8-row tile) x 512 thr (round-13, unchanged).
__global__ __launch_bounds__(512) void gat_prep(
    const float* __restrict__ h, const float* __restrict__ lin_w,
    const float* __restrict__ lin_b, const float* __restrict__ W_w,
    const float* __restrict__ a_g,
    float* __restrict__ hp_g, float* __restrict__ u_out, float* __restrict__ vT_g,
    float* __restrict__ au_out, float* __restrict__ av_out) {
  __shared__ float wlT[64 * 65];  // [k][o] = lin_w[o][k]
  __shared__ float w1T[64 * 65];
  __shared__ float w2T[64 * 65];
  __shared__ float hs[512];       // [n][k]
  __shared__ float hp_s[512];
  __shared__ float v_s[64 * 9];   // [f][n] stride 9
  __shared__ float a_s[64];

  const int b = blockIdx.x >> 7;
  const int n0 = (blockIdx.x & 127) << 3;
  const int tid = threadIdx.x;
  const int lane = tid & 63, w = tid >> 6;
  const int tn = w, tf = lane;

  if (tid < 64) a_s[tid] = a_g[tid];
  for (int idx = tid; idx < 4096; idx += 512) {
    const int o = idx >> 6, k = idx & 63;
    wlT[k * 65 + o] = lin_w[idx];
    w1T[k * 65 + o] = W_w[o * 128 + k];
    w2T[k * 65 + o] = W_w[o * 128 + 64 + k];
  }
  hs[tid] = h[(((b << 10) + n0) << 6) + tid];
  __syncthreads();

  float hpv = lin_b[tf];
#pragma unroll 8
  for (int k = 0; k < 64; ++k)
    hpv = fmaf(hs[tn * 64 + k], wlT[k * 65 + tf], hpv);
  const int row = (b << 10) + n0 + tn;
  hp_g[(row << 6) + tf] = hpv;
  hp_s[tn * 64 + tf] = hpv;
  __syncthreads();

  float uu = 0.f, vv = 0.f;
#pragma unroll 8
  for (int k = 0; k < 64; ++k) {
    const float hh = hp_s[tn * 64 + k];
    uu = fmaf(hh, w1T[k * 65 + tf], uu);
    vv = fmaf(hh, w2T[k * 65 + tf], vv);
  }
  u_out[(row << 6) + tf] = uu;
  v_s[tf * 9 + tn] = vv;
  float aup = a_s[tf] * uu, avp = a_s[tf] * vv;
#pragma unroll
  for (int off = 32; off; off >>= 1) {
    aup += __shfl_xor(aup, off);
    avp += __shfl_xor(avp, off);
  }
  if (tf == 0) {
    au_out[row] = aup;
    av_out[row] = avp;
  }
  __syncthreads();
  {
    const int f = tid >> 3, n = tid & 7;
    vT_g[(((b << 6) + f) << 10) + n0 + n] = v_s[f * 9 + n];
  }
}

// ---------- attn: 1024 blocks (b x 4-row tile) x 512 threads (8 waves).
// 4 blocks/CU x 8 waves = 32 waves/CU cap (100% occupancy ceiling).
// Phase 1/2: thread owns j = 2*tid, 2*tid+1.
// Phase 3: thread = (f-quad fq of 16, j-subgroup g of 32).
__global__ __launch_bounds__(512) void gat_attn(
    const float* __restrict__ u_g, const float* __restrict__ vT,
    const float* __restrict__ hp, const int* __restrict__ adj,
    const float* __restrict__ a_g, const float* __restrict__ au_g,
    const float* __restrict__ av_g, float* __restrict__ out) {
  __shared__ float p_s[4 * 1024];   // [j&1][j>>1][4i] planes: 16 KB
  __shared__ float wp_s[8 * 256];   // wave partials [w][i][f]: 8 KB
  __shared__ float u_s[64 * 4];     // [f][i]
  __shared__ float a_s[64];
  __shared__ float au_s[4];
  __shared__ float wred[8][4];      // [wave][i]
  __shared__ float wsum[8][4];
  __shared__ float rinv_s[4];

  const int b = blockIdx.x >> 8;
  const int i0 = (blockIdx.x & 255) << 2;
  const int tid = threadIdx.x;
  const int lane = tid & 63, w = tid >> 6;
  const int j0 = tid << 1;   // 2 j's per thread

  if (tid < 64) a_s[tid] = a_g[tid];
  if (tid < 4) au_s[tid] = au_g[(b << 10) + i0 + tid];
  if (tid < 256) {
    const int i = tid >> 6, f = tid & 63;
    u_s[f * 4 + i] = u_g[((b << 10) + i0 + i) * 64 + f];
  }
  __syncthreads();

  // ---- Phase 1: d[i][k] = sum_f a_f * |u_if + v_(j0+k)f| ----
  float e[4][2];
#pragma unroll
  for (int i = 0; i < 4; ++i) { e[i][0] = 0.f; e[i][1] = 0.f; }

  const float* vb = vT + ((b << 6) << 10) + j0;
#pragma unroll 4
  for (int f = 0; f < 64; ++f) {
    const float af = a_s[f];
    const float2 v2 = *(const float2*)&vb[f << 10];
    const float4 u4 = *(const float4*)&u_s[f * 4];
    const float uu[4] = {u4.x, u4.y, u4.z, u4.w};
    const float vv[2] = {v2.x, v2.y};
#pragma unroll
    for (int i = 0; i < 4; ++i) {
      e[i][0] = fmaf(af, fabsf(uu[i] + vv[0]), e[i][0]);
      e[i][1] = fmaf(af, fabsf(uu[i] + vv[1]), e[i][1]);
    }
  }
  // e = 0.6(au+av) + 0.4 d, then adjacency mask (int2 per row)
  const float2 av2 = *(const float2*)&av_g[(b << 10) + j0];
  const float avv[2] = {0.6f * av2.x, 0.6f * av2.y};
  float au6[4];
#pragma unroll
  for (int i = 0; i < 4; ++i) au6[i] = 0.6f * au_s[i];
  const int* adjb = adj + (((b << 10) + i0) << 10) + j0;
#pragma unroll
  for (int i = 0; i < 4; ++i) {
    const int2 ad = *(const int2*)&adjb[i << 10];
    const float e0 = fmaf(0.4f, e[i][0], au6[i] + avv[0]);
    const float e1 = fmaf(0.4f, e[i][1], au6[i] + avv[1]);
    e[i][0] = ad.x > 0 ? e0 : NEGINF;
    e[i][1] = ad.y > 0 ? e1 : NEGINF;
  }

  // ---- Phase 2: softmax in registers ----
#pragma unroll
  for (int i = 0; i < 4; ++i) {
    float mm = fmaxf(e[i][0], e[i][1]);
#pragma unroll
    for (int off = 32; off; off >>= 1) mm = fmaxf(mm, __shfl_xor(mm, off));
    if (lane == 0) wred[w][i] = mm;
  }
  __syncthreads();
#pragma unroll
  for (int i = 0; i < 4; ++i) {
    float mi = wred[0][i];
#pragma unroll
    for (int ww = 1; ww < 8; ++ww) mi = fmaxf(mi, wred[ww][i]);
    e[i][0] = __expf(e[i][0] - mi);
    e[i][1] = __expf(e[i][1] - mi);
    float ss = e[i][0] + e[i][1];
#pragma unroll
    for (int off = 32; off; off >>= 1) ss += __shfl_xor(ss, off);
    if (lane == 0) wsum[w][i] = ss;
  }
  __syncthreads();
  if (tid < 4) {
    float st = 0.f;
#pragma unroll
    for (int ww = 0; ww < 8; ++ww) st += wsum[ww][tid];
    rinv_s[tid] = 1.0f / st;
  }
  // p planes: j even -> plane 0 granule j/2, j odd -> plane 1 granule j/2.
  // Store: both at (tid<<2) within plane -> lane-consecutive 16B, conflict-free.
  *(float4*)&p_s[tid << 2] = make_float4(e[0][0], e[1][0], e[2][0], e[3][0]);
  *(float4*)&p_s[2048 + (tid << 2)] =
      make_float4(e[0][1], e[1][1], e[2][1], e[3][1]);
  __syncthreads();

  // ---- Phase 3: h' = p @ hp ; thread = (fq of 16, j-subgroup g of 32) ----
  const int fq = tid & 15, g = tid >> 4;
  float4 acc[4];
#pragma unroll
  for (int i = 0; i < 4; ++i) acc[i] = make_float4(0.f, 0.f, 0.f, 0.f);
  const float* hpb = hp + (b << 16) + (fq << 2);
#pragma unroll 4
  for (int jj = 0; jj < 32; ++jj) {
    const int j = (jj << 5) + g;
    const float4 h4 = *(const float4*)&hpb[j << 6];
    const float4 p4 = *(const float4*)&p_s[((j & 1) << 11) + ((j >> 1) << 2)];
    acc[0].x = fmaf(p4.x, h4.x, acc[0].x);
    acc[0].y = fmaf(p4.x, h4.y, acc[0].y);
    acc[0].z = fmaf(p4.x, h4.z, acc[0].z);
    acc[0].w = fmaf(p4.x, h4.w, acc[0].w);
    acc[1].x = fmaf(p4.y, h4.x, acc[1].x);
    acc[1].y = fmaf(p4.y, h4.y, acc[1].y);
    acc[1].z = fmaf(p4.y, h4.z, acc[1].z);
    acc[1].w = fmaf(p4.y, h4.w, acc[1].w);
    acc[2].x = fmaf(p4.z, h4.x, acc[2].x);
    acc[2].y = fmaf(p4.z, h4.y, acc[2].y);
    acc[2].z = fmaf(p4.z, h4.z, acc[2].z);
    acc[2].w = fmaf(p4.z, h4.w, acc[2].w);
    acc[3].x = fmaf(p4.w, h4.x, acc[3].x);
    acc[3].y = fmaf(p4.w, h4.y, acc[3].y);
    acc[3].z = fmaf(p4.w, h4.z, acc[3].z);
    acc[3].w = fmaf(p4.w, h4.w, acc[3].w);
  }
  // reduce over the 4 j-subgroups within this wave (lane bits 4,5)
#pragma unroll
  for (int i = 0; i < 4; ++i) {
#pragma unroll
    for (int off = 16; off <= 32; off <<= 1) {
      acc[i].x += __shfl_xor(acc[i].x, off);
      acc[i].y += __shfl_xor(acc[i].y, off);
      acc[i].z += __shfl_xor(acc[i].z, off);
      acc[i].w += __shfl_xor(acc[i].w, off);
    }
  }
  if (lane < 16) {
#pragma unroll
    for (int i = 0; i < 4; ++i)
      *(float4*)&wp_s[((w << 2) + i) << 6 | (fq << 2)] = acc[i];
  }
  __syncthreads();
  if (tid < 256) {
    const int i = tid >> 6, f = tid & 63;
    float r = 0.f;
#pragma unroll
    for (int ww = 0; ww < 8; ++ww) r += wp_s[((ww << 2) + i) << 6 | f];
    r *= rinv_s[i];
    out[((b << 10) + i0 + i) * 64 + f] = r > 0.f ? r : expm1f(r);
  }
}

extern "C" void kernel_launch(void* const* d_in, const int* in_sizes, int n_in,
                              void* d_out, int out_size, void* d_ws, size_t ws_size,
                              hipStream_t stream) {
  const float* h = (const float*)d_in[0];
  const int* adj = (const int*)d_in[1];
  const float* lin_w = (const float*)d_in[2];
  const float* lin_b = (const float*)d_in[3];
  const float* W_w = (const float*)d_in[4];
  const float* a = (const float*)d_in[5];
  float* outp = (float*)d_out;

  float* ws = (float*)d_ws;
  float* hp = ws;                 // 262144
  float* u = ws + 262144;         // 262144
  float* vT = ws + 524288;        // 262144
  float* au = ws + 786432;        // 4096
  float* av = ws + 790528;        // 4096

  gat_prep<<<dim3(512), dim3(512), 0, stream>>>(h, lin_w, lin_b, W_w, a,
                                                hp, u, vT, au, av);
  gat_attn<<<dim3(1024), dim3(512), 0, stream>>>(u, vT, hp, adj, a, au, av, outp);
}